// Round 1
// baseline (239.503 us; speedup 1.0000x reference)
//
#include <hip/hip_runtime.h>

#define NPTS  64
#define NANG  2016          // 64*63/2
#define NCOLS 300000
#define RLD   (NPTS + 1)    // padded LDS leading dim: kills bank conflicts

// ---------------------------------------------------------------------------
// Kernel 1: build R^T (with mus folded in) into d_ws.
// One wave (64 threads). Lane c owns column c of R. In triu (top,btm) order,
// group t keeps row t in a register (serial FMA chain ~2016 deep); each row b
// is read+written once per group via LDS. No cross-lane deps inside the chain.
// Output: RT[r*64 + i] = mus[i] * R[i][r]  (transposed for contiguous/uniform
// reads in the matmul kernel).
// ---------------------------------------------------------------------------
__global__ __launch_bounds__(64) void ortho_build_R(
    const float* __restrict__ angles, const float* __restrict__ mus,
    float* __restrict__ RT_out)
{
    __shared__ float s_c[NANG];
    __shared__ float s_s[NANG];
    __shared__ float R[NPTS * RLD];

    const int lane = threadIdx.x;

    // precompute cos/sin (accurate libm sincosf; 32 per lane)
    for (int k = lane; k < NANG; k += 64) {
        float s, c;
        sincosf(angles[k], &s, &c);
        s_c[k] = c;
        s_s[k] = s;
    }
    // init identity, lane c = column c
    #pragma unroll
    for (int i = 0; i < NPTS; ++i)
        R[i * RLD + lane] = (i == lane) ? 1.0f : 0.0f;
    __syncthreads();

    // sequential Givens chain, lexicographic (t,b) order
    int k = 0;
    for (int t = 0; t < NPTS - 1; ++t) {
        float rt = R[t * RLD + lane];
        for (int b = t + 1; b < NPTS; ++b, ++k) {
            const float c = s_c[k];
            const float s = s_s[k];
            const float rb = R[b * RLD + lane];
            R[b * RLD + lane] = fmaf(s, rt, c * rb);   // new row b (uses old rt)
            rt = fmaf(c, rt, -s * rb);                 // serial chain: 1 fma deep
        }
        R[t * RLD + lane] = rt;   // row t is final after its group
    }
    __syncthreads();

    // write transposed + mus scaling; lane c reads its own row c of R
    const float m = mus[lane];
    #pragma unroll
    for (int r = 0; r < NPTS; ++r)
        RT_out[r * NPTS + lane] = m * R[lane * RLD + r];
}

// ---------------------------------------------------------------------------
// Kernel 2: Y = R @ X, one column per thread.
// acc[64] in VGPRs; X loads coalesced (lane j -> X[r*NCOLS + j]); RT reads are
// wave-uniform (__restrict__ + uniform indices -> s_load path, SGPR operand
// in v_fma).
// ---------------------------------------------------------------------------
__global__ __launch_bounds__(256) void ortho_apply(
    const float* __restrict__ X, const float* __restrict__ RT,
    float* __restrict__ Y)
{
    const int j = blockIdx.x * 256 + threadIdx.x;
    if (j >= NCOLS) return;

    float acc[NPTS];
    #pragma unroll
    for (int i = 0; i < NPTS; ++i) acc[i] = 0.0f;

    const float* xp = X + j;
    #pragma unroll 8
    for (int r = 0; r < NPTS; ++r) {
        const float xr = xp[(size_t)r * NCOLS];
        #pragma unroll
        for (int i = 0; i < NPTS; ++i)
            acc[i] = fmaf(RT[r * NPTS + i], xr, acc[i]);
    }

    float* yp = Y + j;
    #pragma unroll
    for (int i = 0; i < NPTS; ++i)
        yp[(size_t)i * NCOLS] = acc[i];
}

// ---------------------------------------------------------------------------
extern "C" void kernel_launch(void* const* d_in, const int* in_sizes, int n_in,
                              void* d_out, int out_size, void* d_ws, size_t ws_size,
                              hipStream_t stream) {
    const float* X      = (const float*)d_in[0];   // 64 x 300000
    const float* angles = (const float*)d_in[1];   // 2016
    const float* mus    = (const float*)d_in[2];   // 64
    float* Y  = (float*)d_out;                     // 64 x 300000
    float* RT = (float*)d_ws;                      // 64 x 64 scratch

    ortho_build_R<<<1, 64, 0, stream>>>(angles, mus, RT);

    const int nblk = (NCOLS + 255) / 256;          // 1172
    ortho_apply<<<nblk, 256, 0, stream>>>(X, RT, Y);
}

// Round 2
// 225.019 us; speedup vs baseline: 1.0644x; 1.0644x over previous
//
#include <hip/hip_runtime.h>

#define NPTS  64
#define NANG  2016          // 64*63/2
#define NCOLS 300000

// ---------------------------------------------------------------------------
// Kernel 1: build A^T = (diag(mus)@R)^T into d_ws, A^T[k][row] contiguous in row.
// One wave. Lane c owns COLUMN c of R, kept entirely in REGISTERS (R[64],
// fully unrolled so all indices are compile-time constants -> no scratch).
// Serial dependency = the rt FMA chain only (~2016 x 4 cyc ~ 3.5 us).
// cos/sin staged once into LDS as interleaved (c,s) pairs; those ds_read_b64s
// are not on the dependency chain (static addresses -> issued ahead).
// ---------------------------------------------------------------------------
__global__ __launch_bounds__(64) void ortho_build_R(
    const float* __restrict__ angles, const float* __restrict__ mus,
    float* __restrict__ AT_out)
{
    __shared__ float2 s_cs[NANG];   // (cos, sin) per rotation, 16 KB

    const int lane = threadIdx.x;

    for (int k = lane; k < NANG; k += 64) {
        float s, c;
        sincosf(angles[k], &s, &c);
        s_cs[k] = make_float2(c, s);
    }
    __syncthreads();

    // column `lane` of R in registers
    float R[NPTS];
    #pragma unroll
    for (int i = 0; i < NPTS; ++i)
        R[i] = (i == lane) ? 1.0f : 0.0f;

    // sequential Givens chain, lexicographic (t,b); fully unrolled
    #pragma unroll
    for (int t = 0; t < NPTS - 1; ++t) {
        float rt = R[t];
        #pragma unroll
        for (int b = t + 1; b < NPTS; ++b) {
            const int k = t * NPTS - (t * (t + 1)) / 2 + (b - t - 1);
            const float2 cs = s_cs[k];
            const float rb = R[b];
            R[b] = fmaf(cs.y, rt, cs.x * rb);    // new row b (old rt)
            rt   = fmaf(cs.x, rt, -cs.y * rb);   // serial chain
        }
        R[t] = rt;
    }

    // Lane L holds R[i][L] for all i. AT[k=L][i] = mus[i]*R[i][L] -> lane L
    // writes 64 consecutive floats at AT_out + L*64 (float4 x16).
    float4* out4 = (float4*)(AT_out + lane * NPTS);
    #pragma unroll
    for (int q = 0; q < 16; ++q) {
        float4 v;
        v.x = mus[q * 4 + 0] * R[q * 4 + 0];
        v.y = mus[q * 4 + 1] * R[q * 4 + 1];
        v.z = mus[q * 4 + 2] * R[q * 4 + 2];
        v.w = mus[q * 4 + 3] * R[q * 4 + 3];
        out4[q] = v;
    }
}

// ---------------------------------------------------------------------------
// Kernel 2: Y = A @ X.  A(64x64) staged in LDS (AT[k][row]); each thread
// computes a 16-row x 4-col tile (float4 acc[16] = 64 VGPRs).
// Block = 256 threads = 64 thread-cols (tc) x 4 thread-rows (tr).
// X loads: coalesced float4 (lane tc -> cols j..j+3).
// A loads: 4x ds_read_b128, wave-uniform address -> broadcast, conflict-free.
// ---------------------------------------------------------------------------
__global__ __launch_bounds__(256) void ortho_apply(
    const float* __restrict__ X, const float* __restrict__ AT,
    float* __restrict__ Y)
{
    __shared__ float sA[NPTS * NPTS];   // sA[k*64 + row], 16 KB

    {   // stage AT -> LDS, coalesced float4
        const float4* src = (const float4*)AT;
        float4* dst = (float4*)sA;
        #pragma unroll
        for (int v = 0; v < 4; ++v)
            dst[v * 256 + threadIdx.x] = src[v * 256 + threadIdx.x];
    }
    __syncthreads();

    const int tc = threadIdx.x & 63;
    const int tr = threadIdx.x >> 6;          // 0..3
    const int j  = blockIdx.x * 256 + tc * 4; // this thread's 4 columns
    if (j >= NCOLS) return;
    const int r0 = tr * 16;                   // this thread's 16 rows

    float4 acc[16];
    #pragma unroll
    for (int i = 0; i < 16; ++i) acc[i] = make_float4(0.f, 0.f, 0.f, 0.f);

    const float4* xcol = (const float4*)(X + j);   // row stride NCOLS/4

#define FMA4(ACC, S) \
    ACC.x = fmaf(S, x.x, ACC.x); ACC.y = fmaf(S, x.y, ACC.y); \
    ACC.z = fmaf(S, x.z, ACC.z); ACC.w = fmaf(S, x.w, ACC.w)

    #pragma unroll 4
    for (int k = 0; k < NPTS; ++k) {
        const float4 x = xcol[k * (NCOLS / 4)];
        const float4* arow = (const float4*)(&sA[k * NPTS + r0]);
        #pragma unroll
        for (int q = 0; q < 4; ++q) {
            const float4 a = arow[q];
            FMA4(acc[q * 4 + 0], a.x);
            FMA4(acc[q * 4 + 1], a.y);
            FMA4(acc[q * 4 + 2], a.z);
            FMA4(acc[q * 4 + 3], a.w);
        }
    }
#undef FMA4

    #pragma unroll
    for (int i = 0; i < 16; ++i)
        *(float4*)(Y + (size_t)(r0 + i) * NCOLS + j) = acc[i];
}

// ---------------------------------------------------------------------------
extern "C" void kernel_launch(void* const* d_in, const int* in_sizes, int n_in,
                              void* d_out, int out_size, void* d_ws, size_t ws_size,
                              hipStream_t stream) {
    const float* X      = (const float*)d_in[0];   // 64 x 300000
    const float* angles = (const float*)d_in[1];   // 2016
    const float* mus    = (const float*)d_in[2];   // 64
    float* Y  = (float*)d_out;                     // 64 x 300000
    float* AT = (float*)d_ws;                      // 64 x 64 scratch

    ortho_build_R<<<1, 64, 0, stream>>>(angles, mus, AT);

    // 75000 float4 columns, 64 per block
    const int nblk = (75000 + 63) / 64;            // 1172
    ortho_apply<<<nblk, 256, 0, stream>>>(X, AT, Y);
}

// Round 4
// 219.116 us; speedup vs baseline: 1.0930x; 1.0269x over previous
//
#include <hip/hip_runtime.h>

#define NPTS  64
#define NANG  2016          // 64*63/2
#define NCOLS 300000
#define NC4   (NCOLS / 4)   // 75000 float4 columns

typedef float v4 __attribute__((ext_vector_type(4)));

// ---------------------------------------------------------------------------
// Kernel 1: build A^T (mus folded) into d_ws as AT[k*64 + row] = mus[row]*R[row][k].
// One wave; lane = column k of R. Shift-register trick: S[i] holds row (t+i);
// each rotation writes its result to S[i-1] (the shift is free), so the outer
// t-loop stays ROLLED (code ~7 KB, fits 32 KB I$ -- R2's full unroll was
// ~100 KB straight-line and thrashed I$ at 1 wave -> 85 us) while S stays in
// registers (inner loop unrolled -> compile-time indices).
// Groups are padded to fixed inner lengths per phase with identity rotations
// (c=1,s=0) from the LDS table; identity still performs the shift.
// Critical path: ~2500 dependent fma (~4cyc) ~ 4 us.
// ---------------------------------------------------------------------------
template<int LEN>
__device__ __forceinline__ void run_groups(float (&S)[NPTS], int t0, int t1,
                                           const float2* __restrict__ cs_tab,
                                           const float* __restrict__ mus,
                                           float* __restrict__ AT_out, int lane)
{
    for (int t = t0; t < t1; ++t) {
        float rt = S[0];
        const float2* csr = cs_tab + t * 63;
        #pragma unroll
        for (int i = 1; i <= LEN; ++i) {
            const float2 cs = csr[i - 1];
            const float rb = S[i];
            S[i - 1] = fmaf(cs.y, rt, cs.x * rb);   // new row (t+i), pre-shifted
            rt       = fmaf(cs.x, rt, -cs.y * rb);  // serial chain
        }
        AT_out[lane * NPTS + t] = mus[t] * rt;      // row t finished
    }
}

__global__ __launch_bounds__(64) void ortho_build_R(
    const float* __restrict__ angles, const float* __restrict__ mus,
    float* __restrict__ AT_out)
{
    __shared__ float2 cs_tab[63 * 63];   // (c,s) for (t, i=1..63); identity if b>=64

    const int lane = threadIdx.x;

    for (int idx = lane; idx < 63 * 63; idx += 64) {
        const int t   = idx / 63;
        const int im1 = idx % 63;
        const int b   = t + im1 + 1;
        float c = 1.0f, s = 0.0f;
        if (b < NPTS) {
            const int k = 63 * t - (t * (t - 1)) / 2 + im1;  // lexicographic index
            sincosf(angles[k], &s, &c);
        }
        cs_tab[idx] = make_float2(c, s);
    }
    __syncthreads();

    float S[NPTS];
    #pragma unroll
    for (int i = 0; i < NPTS; ++i)
        S[i] = (i == lane) ? 1.0f : 0.0f;

    // phase inner length must be >= 63 - t at phase start
    run_groups<63>(S,  0, 16, cs_tab, mus, AT_out, lane);
    run_groups<47>(S, 16, 32, cs_tab, mus, AT_out, lane);
    run_groups<31>(S, 32, 48, cs_tab, mus, AT_out, lane);
    run_groups<15>(S, 48, 63, cs_tab, mus, AT_out, lane);

    AT_out[lane * NPTS + 63] = mus[63] * S[0];       // last row
}

// ---------------------------------------------------------------------------
// Kernel 2: Y = A @ X. No LDS (R2's DS pipe was the 88us bottleneck:
// 256 ds_read_b128/wave x 12cyc x 18 waves/CU = ~23us of pure DS issue).
// Thread tile = 16 rows x 4 cols. A reads are wave-uniform-address global
// loads (L1-resident 16 KB working set); X loads coalesced float4,
// double-buffered 4-deep. step() is a function, NOT a macro -- the R3 macro
// shadowed the caller's loop variable and silently mismatched x with A rows.
// ---------------------------------------------------------------------------
__device__ __forceinline__ void step16(v4 (&acc)[16], const float* __restrict__ Ak,
                                       const v4 xv)
{
    #pragma unroll
    for (int q = 0; q < 4; ++q) {
        const v4 a = *(const v4*)(Ak + 4 * q);
        acc[4 * q + 0] += xv * a.x;
        acc[4 * q + 1] += xv * a.y;
        acc[4 * q + 2] += xv * a.z;
        acc[4 * q + 3] += xv * a.w;
    }
}

__global__ __launch_bounds__(256) void ortho_apply(
    const float* __restrict__ X, const float* __restrict__ AT,
    float* __restrict__ Y)
{
    const int tc = threadIdx.x & 63;
    const int wv = threadIdx.x >> 6;
    const int tr = __builtin_amdgcn_readfirstlane(wv);   // wave-uniform 0..3
    const int r0 = tr * 16;

    const int j4 = blockIdx.x * 64 + tc;                 // float4 column index
    if (j4 >= NC4) return;

    const v4* xp = (const v4*)X + j4;                    // row stride NC4

    v4 acc[16];
    #pragma unroll
    for (int i = 0; i < 16; ++i) acc[i] = (v4)0.0f;

    v4 xa[4], xb[4];
    #pragma unroll
    for (int q = 0; q < 4; ++q) xa[q] = xp[q * NC4];

    for (int k0 = 0; k0 < NPTS; k0 += 8) {
        #pragma unroll
        for (int q = 0; q < 4; ++q) xb[q] = xp[(k0 + 4 + q) * NC4];
        #pragma unroll
        for (int q = 0; q < 4; ++q) step16(acc, AT + (k0 + q) * NPTS + r0, xa[q]);
        #pragma unroll
        for (int q = 0; q < 4; ++q) xa[q] = xp[((k0 + 8 + q) & 63) * NC4]; // wraps last iter (harmless re-read)
        #pragma unroll
        for (int q = 0; q < 4; ++q) step16(acc, AT + (k0 + 4 + q) * NPTS + r0, xb[q]);
    }

    #pragma unroll
    for (int i = 0; i < 16; ++i) {
        v4* yp = (v4*)(Y + (size_t)(r0 + i) * NCOLS) + j4;
        __builtin_nontemporal_store(acc[i], yp);
    }
}

// ---------------------------------------------------------------------------
extern "C" void kernel_launch(void* const* d_in, const int* in_sizes, int n_in,
                              void* d_out, int out_size, void* d_ws, size_t ws_size,
                              hipStream_t stream) {
    const float* X      = (const float*)d_in[0];   // 64 x 300000
    const float* angles = (const float*)d_in[1];   // 2016
    const float* mus    = (const float*)d_in[2];   // 64
    float* Y  = (float*)d_out;                     // 64 x 300000
    float* AT = (float*)d_ws;                      // 64 x 64 scratch

    ortho_build_R<<<1, 64, 0, stream>>>(angles, mus, AT);

    const int nblk = (NC4 + 63) / 64;              // 1172
    ortho_apply<<<nblk, 256, 0, stream>>>(X, AT, Y);
}

// Round 5
// 208.077 us; speedup vs baseline: 1.1510x; 1.0531x over previous
//
#include <hip/hip_runtime.h>

#define NPTS  64
#define NANG  2016          // 64*63/2
#define NCOLS 300000
#define NC4   (NCOLS / 4)   // 75000 float4 columns

typedef float v4 __attribute__((ext_vector_type(4)));

// ---------------------------------------------------------------------------
// Kernel 1: build A^T (mus folded) into d_ws as AT[k*64 + row] = mus[row]*R[row][k].
// One wave; lane = column of R. Shift-register: S[i] holds row (t+i); each
// rotation writes S[i-1] (the shift is free) so the outer t-loop stays rolled.
// R4 post-mortem: 69us = ~65cyc/rotation of ds_read latency (compiler could
// only keep ~12 cs reads in flight at VGPR=140). Fix: explicit double-buffered
// register prefetch of cs in 16-rotation chunks (8x ds_read_b128 issued one
// chunk ahead -> ~130cyc load-to-use distance), live cs capped at 64 VGPRs by
// construction, __launch_bounds__(64,1) to lift the VGPR cap.
// Groups padded to LEN in {64,48,32,16} with identity rotations (c=1,s=0):
// identity performs a pure shift, junk only moves into already-dead S slots
// (S extended to 65 entries so the i=64 pad access is in-bounds).
// ---------------------------------------------------------------------------
template<int LEN>  // multiple of 16
__device__ __forceinline__ void run_groups(float (&S)[NPTS + 1], int t0, int t1,
                                           const v4* __restrict__ cs_tab,
                                           const float* __restrict__ mus,
                                           float* __restrict__ AT_out, int lane)
{
    for (int t = t0; t < t1; ++t) {
        const v4* csr = cs_tab + t * 32;   // 32 v4 = 64 (c,s) pairs per group
        v4 buf[2][8];
        #pragma unroll
        for (int q = 0; q < 8; ++q) buf[0][q] = csr[q];

        float rt = S[0];
        #pragma unroll
        for (int ch = 0; ch < LEN / 16; ++ch) {
            if (ch + 1 < LEN / 16) {       // prefetch next chunk (compile-time idx)
                #pragma unroll
                for (int q = 0; q < 8; ++q)
                    buf[(ch + 1) & 1][q] = csr[(ch + 1) * 8 + q];
            }
            #pragma unroll
            for (int r = 0; r < 16; ++r) {
                const int i = ch * 16 + r + 1;            // compile-time
                const v4  p = buf[ch & 1][r >> 1];
                const float c = (r & 1) ? p.z : p.x;
                const float s = (r & 1) ? p.w : p.y;
                const float rb = S[i];
                S[i - 1] = fmaf(s, rt, c * rb);           // new row (t+i), pre-shifted
                rt       = fmaf(c, rt, -s * rb);          // serial chain
            }
        }
        AT_out[lane * NPTS + t] = mus[t] * rt;            // row t finished
    }
}

__global__ __launch_bounds__(64, 1) void ortho_build_R(
    const float* __restrict__ angles, const float* __restrict__ mus,
    float* __restrict__ AT_out)
{
    __shared__ v4 cs_tab[63 * 32];   // group t at t*32; (c0,s0,c1,s1) per v4; 32 KB

    const int lane = threadIdx.x;

    // fill (c,s) pairs; identity for padded slots
    float2* cs2 = (float2*)cs_tab;
    for (int idx = lane; idx < 63 * 64; idx += 64) {
        const int t  = idx >> 6;
        const int i1 = idx & 63;                 // i-1
        const int b  = t + i1 + 1;
        float c = 1.0f, s = 0.0f;
        if (b < NPTS) {                          // real rotation
            const int k = 63 * t - (t * (t - 1)) / 2 + i1;
            sincosf(angles[k], &s, &c);
        }
        cs2[t * 64 + i1] = make_float2(c, s);
    }
    __syncthreads();

    float S[NPTS + 1];
    #pragma unroll
    for (int i = 0; i <= NPTS; ++i)
        S[i] = (i == lane) ? 1.0f : 0.0f;

    // phase LEN must be >= 63 - t at phase start (and a multiple of 16)
    run_groups<64>(S,  0, 16, cs_tab, mus, AT_out, lane);
    run_groups<48>(S, 16, 32, cs_tab, mus, AT_out, lane);
    run_groups<32>(S, 32, 48, cs_tab, mus, AT_out, lane);
    run_groups<16>(S, 48, 63, cs_tab, mus, AT_out, lane);

    AT_out[lane * NPTS + 63] = mus[63] * S[0];   // last row
}

// ---------------------------------------------------------------------------
// Kernel 2: Y = A @ X (unchanged from R4 — passed, byte-identical to keep the
// build_R delta attribution clean). Thread tile = 16 rows x 4 cols; A reads
// wave-uniform-address global loads; X coalesced float4, double-buffered.
// ---------------------------------------------------------------------------
__device__ __forceinline__ void step16(v4 (&acc)[16], const float* __restrict__ Ak,
                                       const v4 xv)
{
    #pragma unroll
    for (int q = 0; q < 4; ++q) {
        const v4 a = *(const v4*)(Ak + 4 * q);
        acc[4 * q + 0] += xv * a.x;
        acc[4 * q + 1] += xv * a.y;
        acc[4 * q + 2] += xv * a.z;
        acc[4 * q + 3] += xv * a.w;
    }
}

__global__ __launch_bounds__(256) void ortho_apply(
    const float* __restrict__ X, const float* __restrict__ AT,
    float* __restrict__ Y)
{
    const int tc = threadIdx.x & 63;
    const int wv = threadIdx.x >> 6;
    const int tr = __builtin_amdgcn_readfirstlane(wv);   // wave-uniform 0..3
    const int r0 = tr * 16;

    const int j4 = blockIdx.x * 64 + tc;                 // float4 column index
    if (j4 >= NC4) return;

    const v4* xp = (const v4*)X + j4;                    // row stride NC4

    v4 acc[16];
    #pragma unroll
    for (int i = 0; i < 16; ++i) acc[i] = (v4)0.0f;

    v4 xa[4], xb[4];
    #pragma unroll
    for (int q = 0; q < 4; ++q) xa[q] = xp[q * NC4];

    for (int k0 = 0; k0 < NPTS; k0 += 8) {
        #pragma unroll
        for (int q = 0; q < 4; ++q) xb[q] = xp[(k0 + 4 + q) * NC4];
        #pragma unroll
        for (int q = 0; q < 4; ++q) step16(acc, AT + (k0 + q) * NPTS + r0, xa[q]);
        #pragma unroll
        for (int q = 0; q < 4; ++q) xa[q] = xp[((k0 + 8 + q) & 63) * NC4]; // wraps last iter (harmless)
        #pragma unroll
        for (int q = 0; q < 4; ++q) step16(acc, AT + (k0 + 4 + q) * NPTS + r0, xb[q]);
    }

    #pragma unroll
    for (int i = 0; i < 16; ++i) {
        v4* yp = (v4*)(Y + (size_t)(r0 + i) * NCOLS) + j4;
        __builtin_nontemporal_store(acc[i], yp);
    }
}

// ---------------------------------------------------------------------------
extern "C" void kernel_launch(void* const* d_in, const int* in_sizes, int n_in,
                              void* d_out, int out_size, void* d_ws, size_t ws_size,
                              hipStream_t stream) {
    const float* X      = (const float*)d_in[0];   // 64 x 300000
    const float* angles = (const float*)d_in[1];   // 2016
    const float* mus    = (const float*)d_in[2];   // 64
    float* Y  = (float*)d_out;                     // 64 x 300000
    float* AT = (float*)d_ws;                      // 64 x 64 scratch

    ortho_build_R<<<1, 64, 0, stream>>>(angles, mus, AT);

    const int nblk = (NC4 + 63) / 64;              // 1172
    ortho_apply<<<nblk, 256, 0, stream>>>(X, AT, Y);
}